// Round 2
// 2864.062 us; speedup vs baseline: 2.7681x; 2.7681x over previous
//
#include <hip/hip_runtime.h>
#include <hip/hip_bf16.h>

// QuantizeEncoderLayer: B=8, L=1024, D=1024, H=16, DK=64, DINNER=4096.
#define BSZ   8
#define LSEQ  1024
#define DMOD  1024
#define NHEAD 16
#define DHEAD 64
#define DINN  4096
#define ROWS  (BSZ * LSEQ)   // 8192

typedef __hip_bfloat16 bf16;
typedef __bf16 bf16x8 __attribute__((ext_vector_type(8)));
typedef float f32x4 __attribute__((ext_vector_type(4)));
typedef unsigned short us8 __attribute__((ext_vector_type(8)));

__device__ __forceinline__ float ldf(const float* p, size_t i) { return p[i]; }
__device__ __forceinline__ float ldf(const bf16* p, size_t i) {
  return __bfloat162float(p[i]);
}
__device__ __forceinline__ void stf(float* p, size_t i, float v) { p[i] = v; }
__device__ __forceinline__ void stf(bf16* p, size_t i, float v) {
  p[i] = __float2bfloat16(v);
}
// LSQ forward: round-half-even(clamp(x/a, -128, 127)) * a
__device__ __forceinline__ float lsqf(float x, float a) {
  return rintf(fminf(fmaxf(x / a, -128.f), 127.f)) * a;
}
__device__ __forceinline__ unsigned short f2bf(float f) {
  bf16 h = __float2bfloat16(f);
  unsigned short u;
  __builtin_memcpy(&u, &h, 2);
  return u;
}
__device__ __forceinline__ float bf2f(unsigned short u) {
  bf16 h;
  __builtin_memcpy(&h, &u, 2);
  return __bfloat162float(h);
}
__device__ __forceinline__ float ldres(const float* p, size_t i) { return p[i]; }
__device__ __forceinline__ float ldres(const unsigned short* p, size_t i) {
  return bf2f(p[i]);
}
__device__ __forceinline__ void stc(float* p, size_t i, float v) { p[i] = v; }
__device__ __forceinline__ void stc(unsigned short* p, size_t i, float v) {
  p[i] = f2bf(v);
}

// ---------------------------------------------------------------------------
// Weight prep: W fp32 -> exact-integer bf16 (lsq int); alpha folded into the
// consuming GEMM's epilogue. dup=1 writes each int twice (k-interleaved) to
// pair with hi/lo-split activations.
// ---------------------------------------------------------------------------
__global__ __launch_bounds__(256) void prep_w(const float* __restrict__ w,
                                              const float* __restrict__ aw,
                                              unsigned short* __restrict__ o,
                                              int n, int dup, int lgK) {
  int i = blockIdx.x * 256 + threadIdx.x;
  if (i >= n) return;
  float v = rintf(fminf(fmaxf(w[i] / aw[0], -128.f), 127.f));
  unsigned short b = f2bf(v);  // |int| <= 128: exact in bf16
  if (dup) {
    int r = i >> lgK, c = i & ((1 << lgK) - 1);
    size_t o0 = ((size_t)r << (lgK + 1)) + 2 * (size_t)c;
    o[o0] = b;
    o[o0 + 1] = b;
  } else {
    o[i] = b;
  }
}

// ---------------------------------------------------------------------------
// MFMA GEMM: C = epi( scale * (A @ B^T) ), A[M][K], B[N][K] row-major.
//   tile BM_ x BN_, BK=64, (BM_/64)*(BN_/64) waves, each wave owns 64x64
//   (4x4 fragments of 16x16x32 bf16 MFMA), reg-staged LDS, pad-to-72 rows.
// AMODE 0: A is bf16. AMODE 1: A is fp32, expanded to interleaved hi/lo bf16
//   during staging (K is the doubled effective K; source col = k/2).
// QMODE 0: none; 1: c = lsq(c, alphaA).
// CMODE 0: C[m][n] (row m*ldc+n, +batch off). CMODE 1: V-transpose-dup store
//   vTd[(m>>10)][n][2*(m%1024)+{0,1}] for the PV B-operand.
// Epilogue order: c = acc*sc + bias[n]; lsq; += resid; store.
// Batch offsets: off = (z>>lg)*s1 + (z&((1<<lg)-1))*s2 for A, B, C.
// ---------------------------------------------------------------------------
template <int BM_, int BN_, int AMODE, int QMODE, int CMODE, typename TR,
          typename TC>
__global__ __launch_bounds__((BM_ / 64) * (BN_ / 64) * 64) void gemm_mfma(
    const void* __restrict__ Av, const void* __restrict__ Bv,
    TC* __restrict__ Cv, long lda, long ldb, long ldc, int K,
    const float* __restrict__ s1, float cscale,
    const float* __restrict__ bias, const float* __restrict__ alphaA,
    const TR* __restrict__ resid, long ldrr,
    int lgA, long sA1, long sA2, int lgB, long sB1, long sB2,
    int lgC, long sC1, long sC2) {
  constexpr int WN = BN_ / 64;
  constexpr int NT = (BM_ / 64) * WN * 64;
  __shared__ __align__(16) unsigned short As[BM_ * 72];
  __shared__ __align__(16) unsigned short Bs[BN_ * 72];
  const int tid = threadIdx.x;
  const int wid = tid >> 6, lane = tid & 63;
  const int wm = wid / WN, wn = wid % WN;
  const int lr = lane & 15, kg = lane >> 4;
  const int bm = blockIdx.y * BM_, bn = blockIdx.x * BN_;
  const int z = blockIdx.z;
  const size_t offA = (size_t)(z >> lgA) * (size_t)sA1 +
                      (size_t)(z & ((1 << lgA) - 1)) * (size_t)sA2;
  const size_t offB = (size_t)(z >> lgB) * (size_t)sB1 +
                      (size_t)(z & ((1 << lgB) - 1)) * (size_t)sB2;
  const size_t offC = (size_t)(z >> lgC) * (size_t)sC1 +
                      (size_t)(z & ((1 << lgC) - 1)) * (size_t)sC2;

  f32x4 acc[4][4];
  const f32x4 fz = {0.f, 0.f, 0.f, 0.f};
#pragma unroll
  for (int i = 0; i < 4; ++i)
#pragma unroll
    for (int j = 0; j < 4; ++j) acc[i][j] = fz;

  for (int k0 = 0; k0 < K; k0 += 64) {
    if (AMODE == 0) {
      const unsigned short* A = (const unsigned short*)Av + offA;
      for (int c = tid; c < BM_ * 8; c += NT) {
        const int row = c >> 3, col = (c & 7) * 8;
        *(us8*)&As[row * 72 + col] =
            *(const us8*)(A + (size_t)(bm + row) * lda + k0 + col);
      }
    } else {  // fp32 -> hi/lo bf16 pair (x or softmax P): ~fp32-exact in MFMA
      const float* A = (const float*)Av + offA;
      for (int c = tid; c < BM_ * 8; c += NT) {
        const int row = c >> 3, col = (c & 7) * 8;
        f32x4 v = *(const f32x4*)(A + (size_t)(bm + row) * lda + (k0 >> 1) +
                                  (c & 7) * 4);
        us8 oo;
#pragma unroll
        for (int q = 0; q < 4; ++q) {
          const unsigned short hi = f2bf(v[q]);
          oo[2 * q] = hi;
          oo[2 * q + 1] = f2bf(v[q] - bf2f(hi));
        }
        *(us8*)&As[row * 72 + col] = oo;
      }
    }
    {
      const unsigned short* B = (const unsigned short*)Bv + offB;
      for (int c = tid; c < BN_ * 8; c += NT) {
        const int row = c >> 3, col = (c & 7) * 8;
        *(us8*)&Bs[row * 72 + col] =
            *(const us8*)(B + (size_t)(bn + row) * ldb + k0 + col);
      }
    }
    __syncthreads();
#pragma unroll
    for (int kk = 0; kk < 2; ++kk) {
      bf16x8 af[4], bfr[4];
#pragma unroll
      for (int i = 0; i < 4; ++i)
        af[i] = *(const bf16x8*)&As[(wm * 64 + i * 16 + lr) * 72 + kk * 32 +
                                    kg * 8];
#pragma unroll
      for (int j = 0; j < 4; ++j)
        bfr[j] = *(const bf16x8*)&Bs[(wn * 64 + j * 16 + lr) * 72 + kk * 32 +
                                     kg * 8];
#pragma unroll
      for (int i = 0; i < 4; ++i)
#pragma unroll
        for (int j = 0; j < 4; ++j)
          acc[i][j] = __builtin_amdgcn_mfma_f32_16x16x32_bf16(
              af[i], bfr[j], acc[i][j], 0, 0, 0);
    }
    __syncthreads();
  }

  float sc = cscale;
  if (s1) sc *= s1[0];
  const float aa = alphaA ? alphaA[0] : 1.f;
  // C/D frag layout (m89-verified): col = lane&15, row = (lane>>4)*4 + reg.
#pragma unroll
  for (int i = 0; i < 4; ++i) {
    const int mb = bm + wm * 64 + i * 16 + kg * 4;
#pragma unroll
    for (int j = 0; j < 4; ++j) {
      const int n = bn + wn * 64 + j * 16 + lr;
      const float bv = bias ? bias[n] : 0.f;
      if (CMODE == 0) {
#pragma unroll
        for (int r = 0; r < 4; ++r) {
          float c = acc[i][j][r] * sc + bv;
          if (QMODE == 1) c = lsqf(c, aa);
          if (resid) c += ldres(resid, (size_t)(mb + r) * ldrr + n);
          stc(Cv, offC + (size_t)(mb + r) * ldc + n, c);
        }
      } else {  // V-transpose-dup: vTd[b][n][2l],[2l+1] = v[l][n]
        us8 pk;
#pragma unroll
        for (int r = 0; r < 4; ++r) {
          float c = acc[i][j][r] * sc + bv;
          if (QMODE == 1) c = lsqf(c, aa);
          const unsigned short b = f2bf(c);
          pk[2 * r] = b;
          pk[2 * r + 1] = b;
        }
        const size_t addr = offC + (size_t)(mb >> 10) * 2097152 +
                            (size_t)n * 2048 + 2 * (size_t)(mb & 1023);
        *(us8*)((unsigned short*)Cv + addr) = pk;
      }
    }
  }
}

// ---------------------------------------------------------------------------
// VALU tiled GEMM (kept for the tiny fa-adapter chains only).
// ---------------------------------------------------------------------------
#define QBM 64
#define QBN 64
#define QBK 16

template <typename TA, typename TR, typename TC>
__global__ __launch_bounds__(256) void gemm_q(
    const TA* __restrict__ A, const float* __restrict__ W,
    const float* __restrict__ alpha_w, const float* __restrict__ bias,
    const float* __restrict__ alpha_a, const TR* __restrict__ resid,
    TC* __restrict__ C, int M, int N, int K) {
  __shared__ float As[QBM][QBK + 1];
  __shared__ float Ws[QBN][QBK + 1];
  const int tid = threadIdx.x;
  const int bm = blockIdx.y * QBM;
  const int bn = blockIdx.x * QBN;
  const int tx = tid & 15;
  const int ty = tid >> 4;
  const float aw = alpha_w ? alpha_w[0] : 1.f;

  float acc[4][4] = {};
  for (int k0 = 0; k0 < K; k0 += QBK) {
    for (int i = tid; i < QBM * QBK; i += 256) {
      int r = i >> 4, c = i & 15;
      As[r][c] = ldf(A, (size_t)(bm + r) * K + k0 + c);
    }
    for (int i = tid; i < QBN * QBK; i += 256) {
      int r = i >> 4, c = i & 15;
      float w = W[(size_t)(bn + r) * K + k0 + c];
      if (alpha_w) w = lsqf(w, aw);
      Ws[r][c] = w;
    }
    __syncthreads();
#pragma unroll
    for (int kk = 0; kk < QBK; ++kk) {
      float a[4], b[4];
#pragma unroll
      for (int i = 0; i < 4; ++i) a[i] = As[ty * 4 + i][kk];
#pragma unroll
      for (int j = 0; j < 4; ++j) b[j] = Ws[tx * 4 + j][kk];
#pragma unroll
      for (int i = 0; i < 4; ++i)
#pragma unroll
        for (int j = 0; j < 4; ++j) acc[i][j] += a[i] * b[j];
    }
    __syncthreads();
  }
  const float aa = alpha_a ? alpha_a[0] : 1.f;
#pragma unroll
  for (int i = 0; i < 4; ++i) {
    int m = bm + ty * 4 + i;
#pragma unroll
    for (int j = 0; j < 4; ++j) {
      int n = bn + tx * 4 + j;
      float c = acc[i][j];
      if (bias) c += bias[n];
      if (alpha_a) c = lsqf(c, aa);
      if (resid) c += ldf(resid, (size_t)m * N + n);
      stf(C, (size_t)m * N + n, c);
    }
  }
}

// Row softmax over S (one block per row of 1024), in place in d_out.
__global__ __launch_bounds__(256) void softmax_rows(float* __restrict__ S) {
  __shared__ float red[256];
  const int tid = threadIdx.x;
  float* row = S + (size_t)blockIdx.x * LSEQ;
  float v[4];
  float m = -1e30f;
#pragma unroll
  for (int c = 0; c < 4; ++c) {
    v[c] = row[c * 256 + tid];
    m = fmaxf(m, v[c]);
  }
  red[tid] = m;
  __syncthreads();
  for (int off = 128; off > 0; off >>= 1) {
    if (tid < off) red[tid] = fmaxf(red[tid], red[tid + off]);
    __syncthreads();
  }
  const float mx = red[0];
  __syncthreads();
  float s = 0.f;
#pragma unroll
  for (int c = 0; c < 4; ++c) {
    v[c] = expf(v[c] - mx);
    s += v[c];
  }
  red[tid] = s;
  __syncthreads();
  for (int off = 128; off > 0; off >>= 1) {
    if (tid < off) red[tid] += red[tid + off];
    __syncthreads();
  }
  const float inv = 1.f / red[0];
#pragma unroll
  for (int c = 0; c < 4; ++c) row[c * 256 + tid] = v[c] * inv;
}

// ---------------------------------------------------------------------------
// BatchNorm-as-LN (per-channel stats over 8192 rows), two-stage + apply.
// ---------------------------------------------------------------------------
__global__ __launch_bounds__(256) void bn_partial(const float* __restrict__ X,
                                                  float* __restrict__ psum,
                                                  float* __restrict__ psq) {
  const int c = blockIdx.x * 256 + threadIdx.x;
  const int r0 = blockIdx.y * 256;
  float s = 0.f, q = 0.f;
  for (int r = r0; r < r0 + 256; ++r) {
    float v = X[(size_t)r * DMOD + c];
    s += v;
    q += v * v;
  }
  psum[blockIdx.y * DMOD + c] = s;
  psq[blockIdx.y * DMOD + c] = q;
}

__global__ __launch_bounds__(256) void bn_finalize(
    const float* __restrict__ psum, const float* __restrict__ psq,
    float* __restrict__ meanv, float* __restrict__ rstdv) {
  const int c = blockIdx.x * 256 + threadIdx.x;
  float s = 0.f, q = 0.f;
  for (int j = 0; j < 32; ++j) {
    s += psum[j * DMOD + c];
    q += psq[j * DMOD + c];
  }
  const float m = s / (float)ROWS;
  const float var = q / (float)ROWS - m * m;
  meanv[c] = m;
  rstdv[c] = rsqrtf(var + 1e-6f);
}

template <typename TC>
__global__ __launch_bounds__(256) void bn_apply_lsq(
    const float* __restrict__ X, const float* __restrict__ meanv,
    const float* __restrict__ rstdv, const float* __restrict__ gamma,
    const float* __restrict__ beta, const float* __restrict__ alpha,
    TC* __restrict__ Y) {
  const size_t i = (size_t)blockIdx.x * 256 + threadIdx.x;
  const int c = (int)(i & (DMOD - 1));
  const float aa = alpha[0];
  float o = (X[i] - meanv[c]) * rstdv[c] * gamma[c] + beta[c];
  stf(Y, i, lsqf(o, aa));
}

// ---------------------------------------------------------------------------
extern "C" void kernel_launch(void* const* d_in, const int* in_sizes, int n_in,
                              void* d_out, int out_size, void* d_ws,
                              size_t ws_size, hipStream_t stream) {
  const float* x      = (const float*)d_in[0];
  const float* wq     = (const float*)d_in[1];
  const float* a_wq   = (const float*)d_in[2];
  const float* wk     = (const float*)d_in[3];
  const float* a_wk   = (const float*)d_in[4];
  const float* wv     = (const float*)d_in[5];
  const float* a_wv   = (const float*)d_in[6];
  const float* wo     = (const float*)d_in[7];
  const float* a_wo   = (const float*)d_in[8];
  const float* a1     = (const float*)d_in[9];
  const float* a2     = (const float*)d_in[10];
  const float* a3     = (const float*)d_in[11];
  const float* a4     = (const float*)d_in[12];
  const float* a5     = (const float*)d_in[13];
  const float* bn1_g  = (const float*)d_in[14];
  const float* bn1_b  = (const float*)d_in[15];
  const float* fa1_w1 = (const float*)d_in[16];
  const float* fa1_b1 = (const float*)d_in[17];
  const float* fa1_w2 = (const float*)d_in[18];
  const float* fa1_b2 = (const float*)d_in[19];
  const float* fa1_w3 = (const float*)d_in[20];
  const float* fa1_b3 = (const float*)d_in[21];
  const float* ffn_w1 = (const float*)d_in[22];
  const float* ffn_b1 = (const float*)d_in[23];
  const float* a_fw1  = (const float*)d_in[24];
  const float* ffn_w2 = (const float*)d_in[25];
  const float* ffn_b2 = (const float*)d_in[26];
  const float* a_fw2  = (const float*)d_in[27];
  const float* f1     = (const float*)d_in[28];
  const float* f2     = (const float*)d_in[29];
  const float* f3     = (const float*)d_in[30];
  const float* bn2_g  = (const float*)d_in[31];
  const float* bn2_b  = (const float*)d_in[32];
  const float* fa2_w1 = (const float*)d_in[33];
  const float* fa2_b1 = (const float*)d_in[34];
  const float* fa2_w2 = (const float*)d_in[35];
  const float* fa2_b2 = (const float*)d_in[36];
  const float* fa2_w3 = (const float*)d_in[37];
  const float* fa2_b3 = (const float*)d_in[38];

  // output tuple (fp32): y(8.39M) | attn(134.2M) | fa1(8.39M) | fa2(8.39M)
  float* out = (float*)d_out;
  float* y_out    = out;
  float* attn_out = out + 8388608ull;
  float* fa1_out  = attn_out + 134217728ull;
  float* fa2_out  = fa1_out + 8388608ull;

  // workspace (~85 MB):
  //  [0,64MB):   qws[0,16) kws[16,32) vTd[32,64)  -> later h (8192x4096 bf16)
  //  [64,80MB):  obn bf16
  //  [80,82):    u1 fp32   [82,84): u2 fp32   [84,85): bn partials
  char* ws = (char*)d_ws;
  unsigned short* qws = (unsigned short*)(ws);
  unsigned short* kws = (unsigned short*)(ws + (16ull << 20));
  unsigned short* vTd = (unsigned short*)(ws + (32ull << 20));
  unsigned short* hws = (unsigned short*)(ws);  // overlays q/k/vTd after PV
  bf16*  obn  = (bf16*)(ws + (64ull << 20));
  float* u1   = (float*)(ws + (80ull << 20));
  float* u2   = (float*)(ws + (82ull << 20));
  float* psum = (float*)(ws + (84ull << 20));
  float* psq   = psum + 32 * DMOD;
  float* meanv = psq + 32 * DMOD;
  float* rstdv = meanv + DMOD;

  // dead-region scratch in d_out (lifetime-checked):
  //  y region (written by bn2 at the end): prepped weights (30MB).
  //  fa1 region (written by fa1_w3): oatt bf16 (16.8MB), dead before fa1.
  //  fa2 region (written by fa2_w3): t1 fp32 (33.5MB), dead before fa2.
  unsigned short* wq2  = (unsigned short*)y_out;       // [1024][2048] dup
  unsigned short* wk2  = wq2 + (2u << 20);
  unsigned short* wv2  = wk2 + (2u << 20);
  unsigned short* wo_i = wv2 + (2u << 20);             // [1024][1024]
  unsigned short* w1_i = wo_i + (1u << 20);            // [4096][1024]
  unsigned short* w2_i = w1_i + (4u << 20);            // [1024][4096]
  unsigned short* oatt = (unsigned short*)fa1_out;
  float* t1 = fa2_out;

  const dim3 blk(256);
  const dim3 g128(DMOD / 128, ROWS / 128, 1);
  const dim3 gf1(DINN / 128, ROWS / 128, 1);
  const dim3 gsc(8, 8, 128);
  const dim3 gpv(1, 4, 128);
  auto grd = [](int M, int N) { return dim3(N / QBN, M / QBM); };
  const float* nulf = nullptr;

  // --- weight prep: exact-int bf16 (alpha folded into epilogues) ---
  prep_w<<<4096, blk, 0, stream>>>(wq, a_wq, wq2, 1 << 20, 1, 10);
  prep_w<<<4096, blk, 0, stream>>>(wk, a_wk, wk2, 1 << 20, 1, 10);
  prep_w<<<4096, blk, 0, stream>>>(wv, a_wv, wv2, 1 << 20, 1, 10);
  prep_w<<<4096, blk, 0, stream>>>(wo, a_wo, wo_i, 1 << 20, 0, 0);
  prep_w<<<16384, blk, 0, stream>>>(ffn_w1, a_fw1, w1_i, 4 << 20, 0, 0);
  prep_w<<<16384, blk, 0, stream>>>(ffn_w2, a_fw2, w2_i, 4 << 20, 0, 0);

  // --- q/k/v projections: hi/lo-split x (Keff=2048) @ int-dup W ---
  gemm_mfma<128, 128, 1, 1, 0, float, unsigned short>
      <<<g128, blk, 0, stream>>>(x, wq2, qws, 1024, 2048, 1024, 2048, a_wq,
                                 1.f, nulf, a1, (const float*)nullptr, 0,
                                 0, 0, 0, 0, 0, 0, 0, 0, 0);
  gemm_mfma<128, 128, 1, 1, 0, float, unsigned short>
      <<<g128, blk, 0, stream>>>(x, wk2, kws, 1024, 2048, 1024, 2048, a_wk,
                                 1.f, nulf, a2, (const float*)nullptr, 0,
                                 0, 0, 0, 0, 0, 0, 0, 0, 0);
  gemm_mfma<128, 128, 1, 1, 1, float, unsigned short>
      <<<g128, blk, 0, stream>>>(x, wv2, vTd, 1024, 2048, 0, 2048, a_wv,
                                 1.f, nulf, a3, (const float*)nullptr, 0,
                                 0, 0, 0, 0, 0, 0, 0, 0, 0);
  // --- attention: S = (q.k)/8 per head -> softmax (in d_out) -> PV ---
  gemm_mfma<128, 128, 0, 0, 0, float, float>
      <<<gsc, blk, 0, stream>>>(qws, kws, attn_out, 1024, 1024, 1024, 64,
                                nulf, 0.125f, nulf, nulf,
                                (const float*)nullptr, 0,
                                4, 1048576, 64, 4, 1048576, 64,
                                0, 1048576, 0);
  softmax_rows<<<128 * LSEQ, blk, 0, stream>>>(attn_out);
  gemm_mfma<256, 64, 1, 0, 0, float, unsigned short>
      <<<gpv, blk, 0, stream>>>(attn_out, vTd, oatt, 1024, 2048, 1024, 2048,
                                nulf, 1.f, nulf, nulf,
                                (const float*)nullptr, 0,
                                0, 1048576, 0, 0, 131072, 0,
                                4, 1048576, 64);
  // --- o = lsq(oatt @ lsq(wo)^T, a4) + x -> t1 (fp32) ---
  gemm_mfma<128, 128, 0, 1, 0, float, float>
      <<<g128, blk, 0, stream>>>(oatt, wo_i, t1, 1024, 1024, 1024, 1024,
                                 a_wo, 1.f, nulf, a4, x, 1024,
                                 0, 0, 0, 0, 0, 0, 0, 0, 0);
  // --- bn1 + lsq(a5) -> obn ---
  bn_partial<<<dim3(DMOD / 256, 32), blk, 0, stream>>>(t1, psum, psq);
  bn_finalize<<<DMOD / 256, blk, 0, stream>>>(psum, psq, meanv, rstdv);
  bn_apply_lsq<bf16><<<ROWS * DMOD / 256, blk, 0, stream>>>(
      t1, meanv, rstdv, bn1_g, bn1_b, a5, obn);
  // --- fa1 adapter chain + residual (tiny: VALU path) ---
  gemm_q<bf16, float, float><<<grd(ROWS, 64), blk, 0, stream>>>(
      obn, fa1_w1, nullptr, fa1_b1, nullptr, nulf, u1, ROWS, 64, DMOD);
  gemm_q<float, float, float><<<grd(ROWS, 64), blk, 0, stream>>>(
      u1, fa1_w2, nullptr, fa1_b2, nullptr, nulf, u2, ROWS, 64, 64);
  gemm_q<float, bf16, float><<<grd(ROWS, DMOD), blk, 0, stream>>>(
      u2, fa1_w3, nullptr, fa1_b3, nullptr, obn, fa1_out, ROWS, DMOD, 64);
  // --- FFN ---
  gemm_mfma<128, 128, 0, 1, 0, float, unsigned short>
      <<<gf1, blk, 0, stream>>>((const void*)obn, w1_i, hws, 1024, 1024,
                                4096, 1024, a_fw1, 1.f, ffn_b1, f1,
                                (const float*)nullptr, 0,
                                0, 0, 0, 0, 0, 0, 0, 0, 0);
  gemm_mfma<128, 128, 0, 1, 0, unsigned short, float>
      <<<g128, blk, 0, stream>>>(hws, w2_i, t1, 4096, 4096, 1024, 4096,
                                 a_fw2, 1.f, ffn_b2, f2,
                                 reinterpret_cast<const unsigned short*>(obn),
                                 1024, 0, 0, 0, 0, 0, 0, 0, 0, 0);
  // --- bn2 + lsq(f3) -> y (overwrites weight scratch) ---
  bn_partial<<<dim3(DMOD / 256, 32), blk, 0, stream>>>(t1, psum, psq);
  bn_finalize<<<DMOD / 256, blk, 0, stream>>>(psum, psq, meanv, rstdv);
  bn_apply_lsq<float><<<ROWS * DMOD / 256, blk, 0, stream>>>(
      t1, meanv, rstdv, bn2_g, bn2_b, f3, y_out);
  // --- fa2 adapter chain on y (overwrites t1 scratch) ---
  gemm_q<float, float, float><<<grd(ROWS, 64), blk, 0, stream>>>(
      y_out, fa2_w1, nullptr, fa2_b1, nullptr, nulf, u1, ROWS, 64, DMOD);
  gemm_q<float, float, float><<<grd(ROWS, 64), blk, 0, stream>>>(
      u1, fa2_w2, nullptr, fa2_b2, nullptr, nulf, u2, ROWS, 64, 64);
  gemm_q<float, float, float><<<grd(ROWS, DMOD), blk, 0, stream>>>(
      u2, fa2_w3, nullptr, fa2_b3, nullptr, y_out, fa2_out, ROWS, DMOD, 64);
}

// Round 3
// 2216.766 us; speedup vs baseline: 3.5764x; 1.2920x over previous
//
#include <hip/hip_runtime.h>
#include <hip/hip_bf16.h>

// QuantizeEncoderLayer: B=8, L=1024, D=1024, H=16, DK=64, DINNER=4096.
#define BSZ   8
#define LSEQ  1024
#define DMOD  1024
#define NHEAD 16
#define DHEAD 64
#define DINN  4096
#define ROWS  (BSZ * LSEQ)   // 8192

typedef __hip_bfloat16 bf16;
typedef __bf16 bf16x8 __attribute__((ext_vector_type(8)));
typedef float f32x4 __attribute__((ext_vector_type(4)));
typedef unsigned short us8 __attribute__((ext_vector_type(8)));

__device__ __forceinline__ float ldf(const float* p, size_t i) { return p[i]; }
__device__ __forceinline__ float ldf(const bf16* p, size_t i) {
  return __bfloat162float(p[i]);
}
__device__ __forceinline__ void stf(float* p, size_t i, float v) { p[i] = v; }
__device__ __forceinline__ void stf(bf16* p, size_t i, float v) {
  p[i] = __float2bfloat16(v);
}
// LSQ forward: round-half-even(clamp(x/a, -128, 127)) * a
__device__ __forceinline__ float lsqf(float x, float a) {
  return rintf(fminf(fmaxf(x / a, -128.f), 127.f)) * a;
}
__device__ __forceinline__ unsigned short f2bf(float f) {
  bf16 h = __float2bfloat16(f);
  unsigned short u;
  __builtin_memcpy(&u, &h, 2);
  return u;
}
__device__ __forceinline__ float bf2f(unsigned short u) {
  bf16 h;
  __builtin_memcpy(&h, &u, 2);
  return __bfloat162float(h);
}
__device__ __forceinline__ float ldres(const float* p, size_t i) { return p[i]; }
__device__ __forceinline__ float ldres(const unsigned short* p, size_t i) {
  return bf2f(p[i]);
}

// T-format: row-major matrix [R][C] bf16 (C mult of 64) stored as 64x64 tiles
// of 4096 ushorts, tile-linear (rb*Ct + cb), within tile slot-major:
// addr = tile*4096 + ((col&63)>>3)*512 + (row&63)*8 + (col&7).
__device__ __forceinline__ size_t taddr(long row, long col, int ct) {
  return (((size_t)(row >> 6) * ct + (col >> 6)) << 12) +
         ((size_t)((col >> 3) & 7) << 9) + ((size_t)(row & 63) << 3) +
         (col & 7);
}

__device__ __forceinline__ void gload_lds16(const unsigned short* g,
                                            unsigned short* l) {
  __builtin_amdgcn_global_load_lds(
      (const __attribute__((address_space(1))) void*)g,
      (__attribute__((address_space(3))) void*)l, 16, 0, 0);
}

// ---------------------------------------------------------------------------
// Weight prep: fp32 W[N][K] -> T-format exact-integer bf16 (alpha folded into
// consumer epilogue). dup=1: logical [N][2K], each int duplicated at cols
// 2k,2k+1 (pairs with hi/lo-split activations). One us8 slot per thread,
// T-linear order (stores fully coalesced).
// ---------------------------------------------------------------------------
__global__ __launch_bounds__(256) void prep_wT(const float* __restrict__ w,
                                               const float* __restrict__ aw,
                                               unsigned short* __restrict__ o,
                                               int Ct, int Kt, int dup) {
  const long idx = (long)blockIdx.x * 256 + threadIdx.x;
  const long tile = idx >> 9;
  const int within = (int)(idx & 511);
  const int c8 = within >> 6, r64 = within & 63;
  const long row = (tile / Ct) * 64 + r64;
  const long col = (tile % Ct) * 64 + c8 * 8;
  const float ainv = 1.f / aw[0];
  us8 oo;
  if (dup) {
    const float* src = w + row * (Kt >> 1) + (col >> 1);
#pragma unroll
    for (int q = 0; q < 4; ++q) {
      float v = rintf(fminf(fmaxf(src[q] * ainv, -128.f), 127.f));
      unsigned short b = f2bf(v);
      oo[2 * q] = b;
      oo[2 * q + 1] = b;
    }
  } else {
    const float* src = w + row * Kt + col;
#pragma unroll
    for (int e = 0; e < 8; ++e) {
      float v = rintf(fminf(fmaxf(src[e] * ainv, -128.f), 127.f));
      oo[e] = f2bf(v);
    }
  }
  *(us8*)&o[idx << 3] = oo;
}

// x fp32 [8192][1024] -> hi/lo split T-format bf16 [8192][2048] (Ct=32).
__global__ __launch_bounds__(256) void split_x(const float* __restrict__ x,
                                               unsigned short* __restrict__ o) {
  const long idx = (long)blockIdx.x * 256 + threadIdx.x;  // 2M slots
  const long tile = idx >> 9;
  const int within = (int)(idx & 511);
  const int c8 = within >> 6, r64 = within & 63;
  const long row = (tile >> 5) * 64 + r64;
  const long colT = (tile & 31) * 64 + c8 * 8;
  f32x4 v = *(const f32x4*)(x + row * 1024 + (colT >> 1));
  us8 oo;
#pragma unroll
  for (int q = 0; q < 4; ++q) {
    const unsigned short hi = f2bf(v[q]);
    oo[2 * q] = hi;
    oo[2 * q + 1] = f2bf(v[q] - bf2f(hi));
  }
  *(us8*)&o[idx << 3] = oo;
}

// ---------------------------------------------------------------------------
// MFMA GEMM on T-format operands: C = epi( scale * (A @ B^T) ).
//   A [M][K], B [N][K] both T-format bf16 (global_load_lds staging), BK=64,
//   (BM_/64)*(BN_/64) waves, wave = 64x64 out (4x4 frags of 16x16x32 bf16).
// GEOM 0: plain (z unused). GEOM 1: scores (A,B row off (z>>4)*1024, col off
//   (z&15)*64; C fp32 + z*2^20). GEOM 2: PV (A fp32 at z*2^20 hi/lo reg-staged,
//   B row off z*64, C T-format row off (z>>4)*1024 col off (z&15)*64).
// AMODE 0: A T-format bf16. AMODE 1: A fp32 row-major (stride 1024), hi/lo
//   expanded during reg staging (K = doubled).
// QMODE 1: c = lsq(c, alphaA). CMODE 0: fp32 row-major (ldc) + optional resid.
//   CMODE 1: bf16 T-format (ldc = CtC). CMODE 2: vTd dup store (V-proj).
// ---------------------------------------------------------------------------
template <int BM_, int BN_, int GEOM, int AMODE, int QMODE, int CMODE,
          typename TR>
__global__ __launch_bounds__((BM_ / 64) * (BN_ / 64) * 64) void gemm_t(
    const void* __restrict__ Av, const void* __restrict__ Bv,
    void* __restrict__ Cv, int K, int CtA, int CtB, int ldc,
    const float* __restrict__ s1, float cscale, const float* __restrict__ bias,
    const float* __restrict__ alphaA, const TR* __restrict__ resid, long ldr) {
  constexpr int AT = BM_ / 64, BT = BN_ / 64, NW = AT * BT;
  __shared__ __align__(16) unsigned short sm[(AT + BT) * 4096];
  const int tid = threadIdx.x;
  const int w = tid >> 6, lane = tid & 63;
  const int wm = w / BT, wn = w % BT;
  const int lr = lane & 15, kg = lane >> 4;
  const int bm = blockIdx.y * BM_, bn = blockIdx.x * BN_;
  const int z = blockIdx.z;

  long Aro = 0, Aco = 0, Bro = 0, Bco = 0, Cro = 0, Cco = 0;
  size_t CoffF = 0, AoffF = 0;
  if (GEOM == 1) {
    Aro = (long)(z >> 4) * 1024;
    Aco = (long)(z & 15) * 64;
    Bro = Aro;
    Bco = Aco;
    CoffF = (size_t)z << 20;
  }
  if (GEOM == 2) {
    AoffF = (size_t)z << 20;
    Bro = (long)z * 64;
    Cro = (long)(z >> 4) * 1024;
    Cco = (long)(z & 15) * 64;
  }

  f32x4 acc[4][4];
  const f32x4 fz = {0.f, 0.f, 0.f, 0.f};
#pragma unroll
  for (int i = 0; i < 4; ++i)
#pragma unroll
    for (int j = 0; j < 4; ++j) acc[i][j] = fz;

  for (int k0 = 0; k0 < K; k0 += 64) {
    if (AMODE == 0) {
      // wave w stages tile w (A tiles 0..AT-1, then B tiles). NW == AT+BT.
      const unsigned short* src;
      if (w < AT) {
        const size_t tile =
            (size_t)((Aro + bm) / 64 + w) * CtA + (size_t)((Aco + k0) / 64);
        src = (const unsigned short*)Av + (tile << 12);
      } else {
        const size_t tile = (size_t)((Bro + bn) / 64 + (w - AT)) * CtB +
                            (size_t)((Bco + k0) / 64);
        src = (const unsigned short*)Bv + (tile << 12);
      }
      unsigned short* dst = &sm[w * 4096];
#pragma unroll
      for (int i = 0; i < 8; ++i)
        gload_lds16(src + i * 512 + lane * 8, dst + i * 512);
    } else {
      // A: fp32 hi/lo reg-stage; wave w -> tile w (rows bm + 64w .. +63).
      const float* Af = (const float*)Av + AoffF;
#pragma unroll
      for (int s = 0; s < 8; ++s) {
        const int u = s * 64 + lane;
        const int row = u >> 3, c8 = u & 7;
        f32x4 p = *(const f32x4*)(Af + (size_t)(bm + w * 64 + row) * 1024 +
                                  (k0 >> 1) + c8 * 4);
        us8 oo;
#pragma unroll
        for (int q = 0; q < 4; ++q) {
          const unsigned short hi = f2bf(p[q]);
          oo[2 * q] = hi;
          oo[2 * q + 1] = f2bf(p[q] - bf2f(hi));
        }
        *(us8*)&sm[w * 4096 + (c8 << 9) + (row << 3)] = oo;
      }
      // B: single tile (BT==1) via distributed global_load_lds.
      const size_t tile = (size_t)((Bro + bn) >> 6) * CtB + (size_t)(k0 >> 6);
      const unsigned short* src = (const unsigned short*)Bv + (tile << 12);
#pragma unroll
      for (int i = 2 * w; i < 2 * w + 2; ++i)
        gload_lds16(src + i * 512 + lane * 8, &sm[AT * 4096 + i * 512]);
    }
    __syncthreads();
#pragma unroll
    for (int kk = 0; kk < 2; ++kk) {
      bf16x8 af[4], bfr[4];
#pragma unroll
      for (int i = 0; i < 4; ++i)
        af[i] = *(const bf16x8*)&sm[wm * 4096 + ((kk * 4 + kg) << 9) +
                                    ((i * 16 + lr) << 3)];
#pragma unroll
      for (int j = 0; j < 4; ++j)
        bfr[j] = *(const bf16x8*)&sm[(AT + wn) * 4096 + ((kk * 4 + kg) << 9) +
                                     ((j * 16 + lr) << 3)];
#pragma unroll
      for (int i = 0; i < 4; ++i)
#pragma unroll
        for (int j = 0; j < 4; ++j)
          acc[i][j] = __builtin_amdgcn_mfma_f32_16x16x32_bf16(
              af[i], bfr[j], acc[i][j], 0, 0, 0);
    }
    __syncthreads();
  }

  float sc = cscale;
  if (s1) sc *= s1[0];
  const float aa = alphaA ? alphaA[0] : 1.f;
  // C/D frag layout: col = lane&15, row = (lane>>4)*4 + reg.
#pragma unroll
  for (int i = 0; i < 4; ++i) {
    const int mb = bm + wm * 64 + i * 16 + kg * 4;
#pragma unroll
    for (int j = 0; j < 4; ++j) {
      const int n = bn + wn * 64 + j * 16 + lr;
      const float bv = bias ? bias[n] : 0.f;
      if (CMODE == 0) {
        float* Cf = (float*)Cv + CoffF;
#pragma unroll
        for (int r = 0; r < 4; ++r) {
          float c = acc[i][j][r] * sc + bv;
          if (QMODE == 1) c = lsqf(c, aa);
          if (resid) c += ldres(resid, (size_t)(mb + r) * ldr + n);
          Cf[(size_t)(mb + r) * ldc + n] = c;
        }
      } else if (CMODE == 1) {
        unsigned short* Ct_ = (unsigned short*)Cv;
#pragma unroll
        for (int r = 0; r < 4; ++r) {
          float c = acc[i][j][r] * sc + bv;
          if (QMODE == 1) c = lsqf(c, aa);
          Ct_[taddr(Cro + mb + r, Cco + n, ldc)] = f2bf(c);
        }
      } else {  // CMODE 2: vTd[b*16+h] 64x2048 T-format, dup cols 2l,2l+1
        us8 pk;
#pragma unroll
        for (int r = 0; r < 4; ++r) {
          float c = acc[i][j][r] * sc + bv;
          if (QMODE == 1) c = lsqf(c, aa);
          const unsigned short b = f2bf(c);
          pk[2 * r] = b;
          pk[2 * r + 1] = b;
        }
        const int bb = mb >> 10, h = n >> 6, d = n & 63;
        const long col0 = 2L * (mb & 1023);
        unsigned short* dst = (unsigned short*)Cv +
                              ((size_t)(bb * 16 + h) << 17) +
                              (((size_t)(col0 >> 6)) << 12) +
                              (((size_t)((col0 >> 3) & 7)) << 9) +
                              ((size_t)d << 3);
        *(us8*)dst = pk;
      }
    }
  }
}

// ---------------------------------------------------------------------------
// VALU tiled GEMM (tiny fa-adapter chains only).
// ---------------------------------------------------------------------------
#define QBM 64
#define QBN 64
#define QBK 16

template <typename TA, typename TR, typename TC>
__global__ __launch_bounds__(256) void gemm_q(
    const TA* __restrict__ A, const float* __restrict__ W,
    const float* __restrict__ alpha_w, const float* __restrict__ bias,
    const float* __restrict__ alpha_a, const TR* __restrict__ resid,
    TC* __restrict__ C, int M, int N, int K) {
  __shared__ float As[QBM][QBK + 1];
  __shared__ float Ws[QBN][QBK + 1];
  const int tid = threadIdx.x;
  const int bm = blockIdx.y * QBM;
  const int bn = blockIdx.x * QBN;
  const int tx = tid & 15;
  const int ty = tid >> 4;
  const float aw = alpha_w ? alpha_w[0] : 1.f;

  float acc[4][4] = {};
  for (int k0 = 0; k0 < K; k0 += QBK) {
    for (int i = tid; i < QBM * QBK; i += 256) {
      int r = i >> 4, c = i & 15;
      As[r][c] = ldf(A, (size_t)(bm + r) * K + k0 + c);
    }
    for (int i = tid; i < QBN * QBK; i += 256) {
      int r = i >> 4, c = i & 15;
      float w = W[(size_t)(bn + r) * K + k0 + c];
      if (alpha_w) w = lsqf(w, aw);
      Ws[r][c] = w;
    }
    __syncthreads();
#pragma unroll
    for (int kk = 0; kk < QBK; ++kk) {
      float a[4], b[4];
#pragma unroll
      for (int i = 0; i < 4; ++i) a[i] = As[ty * 4 + i][kk];
#pragma unroll
      for (int j = 0; j < 4; ++j) b[j] = Ws[tx * 4 + j][kk];
#pragma unroll
      for (int i = 0; i < 4; ++i)
#pragma unroll
        for (int j = 0; j < 4; ++j) acc[i][j] += a[i] * b[j];
    }
    __syncthreads();
  }
  const float aa = alpha_a ? alpha_a[0] : 1.f;
#pragma unroll
  for (int i = 0; i < 4; ++i) {
    int m = bm + ty * 4 + i;
#pragma unroll
    for (int j = 0; j < 4; ++j) {
      int n = bn + tx * 4 + j;
      float c = acc[i][j];
      if (bias) c += bias[n];
      if (alpha_a) c = lsqf(c, aa);
      if (resid) c += ldf(resid, (size_t)m * N + n);
      stf(C, (size_t)m * N + n, c);
    }
  }
}

// Row softmax over S (one block per row of 1024), in place in d_out.
__global__ __launch_bounds__(256) void softmax_rows(float* __restrict__ S) {
  __shared__ float red[256];
  const int tid = threadIdx.x;
  float* row = S + (size_t)blockIdx.x * LSEQ;
  float v[4];
  float m = -1e30f;
#pragma unroll
  for (int c = 0; c < 4; ++c) {
    v[c] = row[c * 256 + tid];
    m = fmaxf(m, v[c]);
  }
  red[tid] = m;
  __syncthreads();
  for (int off = 128; off > 0; off >>= 1) {
    if (tid < off) red[tid] = fmaxf(red[tid], red[tid + off]);
    __syncthreads();
  }
  const float mx = red[0];
  __syncthreads();
  float s = 0.f;
#pragma unroll
  for (int c = 0; c < 4; ++c) {
    v[c] = expf(v[c] - mx);
    s += v[c];
  }
  red[tid] = s;
  __syncthreads();
  for (int off = 128; off > 0; off >>= 1) {
    if (tid < off) red[tid] += red[tid + off];
    __syncthreads();
  }
  const float inv = 1.f / red[0];
#pragma unroll
  for (int c = 0; c < 4; ++c) row[c * 256 + tid] = v[c] * inv;
}

// ---------------------------------------------------------------------------
// BatchNorm-as-LN (per-channel stats over 8192 rows), two-stage + apply.
// ---------------------------------------------------------------------------
__global__ __launch_bounds__(256) void bn_partial(const float* __restrict__ X,
                                                  float* __restrict__ psum,
                                                  float* __restrict__ psq) {
  const int c = blockIdx.x * 256 + threadIdx.x;
  const int r0 = blockIdx.y * 256;
  float s = 0.f, q = 0.f;
  for (int r = r0; r < r0 + 256; ++r) {
    float v = X[(size_t)r * DMOD + c];
    s += v;
    q += v * v;
  }
  psum[blockIdx.y * DMOD + c] = s;
  psq[blockIdx.y * DMOD + c] = q;
}

__global__ __launch_bounds__(256) void bn_finalize(
    const float* __restrict__ psum, const float* __restrict__ psq,
    float* __restrict__ meanv, float* __restrict__ rstdv) {
  const int c = blockIdx.x * 256 + threadIdx.x;
  float s = 0.f, q = 0.f;
  for (int j = 0; j < 32; ++j) {
    s += psum[j * DMOD + c];
    q += psq[j * DMOD + c];
  }
  const float m = s / (float)ROWS;
  const float var = q / (float)ROWS - m * m;
  meanv[c] = m;
  rstdv[c] = rsqrtf(var + 1e-6f);
}

// bn apply + lsq -> bf16, dual write: T-format (for FFN1) + row-major (fa1/
// FFN2-resid). One us8 slot per thread in T-linear order.
__global__ __launch_bounds__(256) void bn_applyT(
    const float* __restrict__ X, const float* __restrict__ meanv,
    const float* __restrict__ rstdv, const float* __restrict__ gamma,
    const float* __restrict__ beta, const float* __restrict__ alpha,
    unsigned short* __restrict__ oT, unsigned short* __restrict__ oR) {
  const long idx = (long)blockIdx.x * 256 + threadIdx.x;  // 1M slots
  const long tile = idx >> 9;
  const int within = (int)(idx & 511);
  const int c8 = within >> 6, r64 = within & 63;
  const long row = (tile >> 4) * 64 + r64;   // Ct = 16
  const int col = (int)((tile & 15) * 64 + c8 * 8);
  const float aa = alpha[0];
  const float* xr = X + row * 1024 + col;
  us8 oo;
#pragma unroll
  for (int e = 0; e < 8; ++e) {
    const int c = col + e;
    float o = (xr[e] - meanv[c]) * rstdv[c] * gamma[c] + beta[c];
    oo[e] = f2bf(lsqf(o, aa));
  }
  *(us8*)&oT[idx << 3] = oo;
  *(us8*)&oR[row * 1024 + col] = oo;
}

template <typename TC>
__global__ __launch_bounds__(256) void bn_apply_lsq(
    const float* __restrict__ X, const float* __restrict__ meanv,
    const float* __restrict__ rstdv, const float* __restrict__ gamma,
    const float* __restrict__ beta, const float* __restrict__ alpha,
    TC* __restrict__ Y) {
  const size_t i = (size_t)blockIdx.x * 256 + threadIdx.x;
  const int c = (int)(i & (DMOD - 1));
  const float aa = alpha[0];
  float o = (X[i] - meanv[c]) * rstdv[c] * gamma[c] + beta[c];
  stf(Y, i, lsqf(o, aa));
}

// ---------------------------------------------------------------------------
extern "C" void kernel_launch(void* const* d_in, const int* in_sizes, int n_in,
                              void* d_out, int out_size, void* d_ws,
                              size_t ws_size, hipStream_t stream) {
  const float* x      = (const float*)d_in[0];
  const float* wq     = (const float*)d_in[1];
  const float* a_wq   = (const float*)d_in[2];
  const float* wk     = (const float*)d_in[3];
  const float* a_wk   = (const float*)d_in[4];
  const float* wv     = (const float*)d_in[5];
  const float* a_wv   = (const float*)d_in[6];
  const float* wo     = (const float*)d_in[7];
  const float* a_wo   = (const float*)d_in[8];
  const float* a1     = (const float*)d_in[9];
  const float* a2     = (const float*)d_in[10];
  const float* a3     = (const float*)d_in[11];
  const float* a4     = (const float*)d_in[12];
  const float* a5     = (const float*)d_in[13];
  const float* bn1_g  = (const float*)d_in[14];
  const float* bn1_b  = (const float*)d_in[15];
  const float* fa1_w1 = (const float*)d_in[16];
  const float* fa1_b1 = (const float*)d_in[17];
  const float* fa1_w2 = (const float*)d_in[18];
  const float* fa1_b2 = (const float*)d_in[19];
  const float* fa1_w3 = (const float*)d_in[20];
  const float* fa1_b3 = (const float*)d_in[21];
  const float* ffn_w1 = (const float*)d_in[22];
  const float* ffn_b1 = (const float*)d_in[23];
  const float* a_fw1  = (const float*)d_in[24];
  const float* ffn_w2 = (const float*)d_in[25];
  const float* ffn_b2 = (const float*)d_in[26];
  const float* a_fw2  = (const float*)d_in[27];
  const float* f1     = (const float*)d_in[28];
  const float* f2     = (const float*)d_in[29];
  const float* f3     = (const float*)d_in[30];
  const float* bn2_g  = (const float*)d_in[31];
  const float* bn2_b  = (const float*)d_in[32];
  const float* fa2_w1 = (const float*)d_in[33];
  const float* fa2_b1 = (const float*)d_in[34];
  const float* fa2_w2 = (const float*)d_in[35];
  const float* fa2_b2 = (const float*)d_in[36];
  const float* fa2_w3 = (const float*)d_in[37];
  const float* fa2_b3 = (const float*)d_in[38];

  // output tuple (fp32): y(8.39M) | attn(134.2M) | fa1(8.39M) | fa2(8.39M)
  float* out = (float*)d_out;
  float* y_out    = out;
  float* attn_out = out + 8388608ull;
  float* fa1_out  = attn_out + 134217728ull;
  float* fa2_out  = fa1_out + 8388608ull;

  // workspace (~101 MiB):
  //  [0,16):  qws T bf16 [8192][1024]        (dead after scores)
  //  [16,32): kws T bf16 [8192][1024]        (dead after scores)
  //  [32,64): vTd T bf16 128x[64][2048] dup  (dead after PV)
  //  [0,64):  hws T bf16 [8192][4096]        (overlay, written by FFN1)
  //  [64,96): xsplit T bf16 [8192][2048]     (dead after QKV)
  //  [64,80): obn_T  (overlay, written after xsplit dead)
  //  [80,96): obn_R
  //  [96+):   u1, u2, bn partials
  char* ws = (char*)d_ws;
  unsigned short* qws    = (unsigned short*)(ws);
  unsigned short* kws    = (unsigned short*)(ws + (16ull << 20));
  unsigned short* vTd    = (unsigned short*)(ws + (32ull << 20));
  unsigned short* hws    = (unsigned short*)(ws);
  unsigned short* xsplit = (unsigned short*)(ws + (64ull << 20));
  unsigned short* obn_T  = (unsigned short*)(ws + (64ull << 20));
  unsigned short* obn_R  = (unsigned short*)(ws + (80ull << 20));
  float* u1   = (float*)(ws + (96ull << 20));
  float* u2   = (float*)(ws + (98ull << 20));
  float* psum = (float*)(ws + (100ull << 20));
  float* psq   = psum + 32 * DMOD;
  float* meanv = psq + 32 * DMOD;
  float* rstdv = meanv + DMOD;

  // dead-region scratch in d_out (lifetime-checked):
  //  y region: prepped weights (30 MiB), all consumed before bn2 writes y.
  //  fa1 region: oatt T bf16 (16 MiB), consumed by wo before fa1 chain.
  //  fa2 region: t1 fp32 (33.5 MiB), consumed by bn2 before fa2 chain.
  unsigned short* wq2  = (unsigned short*)y_out;     // [1024][2048] dup T
  unsigned short* wk2  = wq2 + 2097152ull;
  unsigned short* wv2  = wk2 + 2097152ull;
  unsigned short* wo_i = wv2 + 2097152ull;           // [1024][1024] T
  unsigned short* w1_i = wo_i + 1048576ull;          // [4096][1024] T
  unsigned short* w2_i = w1_i + 4194304ull;          // [1024][4096] T
  unsigned short* oatt = (unsigned short*)fa1_out;   // [8192][1024] T
  float* t1 = fa2_out;

  const dim3 blk(256);
  const dim3 g128(DMOD / 128, ROWS / 128, 1);
  const dim3 gf1(DINN / 128, ROWS / 128, 1);
  const dim3 gsc(8, 8, 128);
  const dim3 gpv(1, 4, 128);
  auto grd = [](int M, int N) { return dim3(N / QBN, M / QBM); };
  const float* nulf = nullptr;

  // --- operand prep (T-format) ---
  split_x<<<8192, blk, 0, stream>>>(x, xsplit);
  prep_wT<<<1024, blk, 0, stream>>>(wq, a_wq, wq2, 32, 2048, 1);
  prep_wT<<<1024, blk, 0, stream>>>(wk, a_wk, wk2, 32, 2048, 1);
  prep_wT<<<1024, blk, 0, stream>>>(wv, a_wv, wv2, 32, 2048, 1);
  prep_wT<<<512,  blk, 0, stream>>>(wo, a_wo, wo_i, 16, 1024, 0);
  prep_wT<<<2048, blk, 0, stream>>>(ffn_w1, a_fw1, w1_i, 16, 1024, 0);
  prep_wT<<<2048, blk, 0, stream>>>(ffn_w2, a_fw2, w2_i, 64, 4096, 0);

  // --- q/k/v projections (Keff=2048, hi/lo x @ dup int W) ---
  gemm_t<128, 128, 0, 0, 1, 1, float><<<g128, blk, 0, stream>>>(
      xsplit, wq2, qws, 2048, 32, 32, 16, a_wq, 1.f, nulf, a1, nulf, 0);
  gemm_t<128, 128, 0, 0, 1, 1, float><<<g128, blk, 0, stream>>>(
      xsplit, wk2, kws, 2048, 32, 32, 16, a_wk, 1.f, nulf, a2, nulf, 0);
  gemm_t<128, 128, 0, 0, 1, 2, float><<<g128, blk, 0, stream>>>(
      xsplit, wv2, vTd, 2048, 32, 32, 0, a_wv, 1.f, nulf, a3, nulf, 0);
  // --- attention: S -> softmax (in d_out) -> PV ---
  gemm_t<128, 128, 1, 0, 0, 0, float><<<gsc, blk, 0, stream>>>(
      qws, kws, attn_out, 64, 16, 16, 1024, nulf, 0.125f, nulf, nulf, nulf, 0);
  softmax_rows<<<128 * LSEQ, blk, 0, stream>>>(attn_out);
  gemm_t<256, 64, 2, 1, 0, 1, float><<<gpv, blk, 0, stream>>>(
      attn_out, vTd, oatt, 2048, 0, 32, 16, nulf, 1.f, nulf, nulf, nulf, 0);
  // --- o = lsq(oatt @ lsq(wo)^T, a4) + x -> t1 (fp32) ---
  gemm_t<128, 128, 0, 0, 1, 0, float><<<g128, blk, 0, stream>>>(
      oatt, wo_i, t1, 1024, 16, 16, 1024, a_wo, 1.f, nulf, a4, x, 1024);
  // --- bn1 + lsq(a5) -> obn (T + R) ---
  bn_partial<<<dim3(DMOD / 256, 32), blk, 0, stream>>>(t1, psum, psq);
  bn_finalize<<<DMOD / 256, blk, 0, stream>>>(psum, psq, meanv, rstdv);
  bn_applyT<<<4096, blk, 0, stream>>>(t1, meanv, rstdv, bn1_g, bn1_b, a5,
                                      obn_T, obn_R);
  // --- fa1 adapter chain + residual (tiny: VALU path) ---
  gemm_q<bf16, float, float><<<grd(ROWS, 64), blk, 0, stream>>>(
      (const bf16*)obn_R, fa1_w1, nullptr, fa1_b1, nullptr, nulf, u1, ROWS, 64,
      DMOD);
  gemm_q<float, float, float><<<grd(ROWS, 64), blk, 0, stream>>>(
      u1, fa1_w2, nullptr, fa1_b2, nullptr, nulf, u2, ROWS, 64, 64);
  gemm_q<float, bf16, float><<<grd(ROWS, DMOD), blk, 0, stream>>>(
      u2, fa1_w3, nullptr, fa1_b3, nullptr, (const bf16*)obn_R, fa1_out, ROWS,
      DMOD, 64);
  // --- FFN ---
  gemm_t<128, 128, 0, 0, 1, 1, float><<<gf1, blk, 0, stream>>>(
      obn_T, w1_i, hws, 1024, 16, 16, 64, a_fw1, 1.f, ffn_b1, f1, nulf, 0);
  gemm_t<128, 128, 0, 0, 1, 0, unsigned short><<<g128, blk, 0, stream>>>(
      hws, w2_i, t1, 4096, 64, 64, 1024, a_fw2, 1.f, ffn_b2, f2, obn_R, 1024);
  // --- bn2 + lsq(f3) -> y (overwrites weight scratch) ---
  bn_partial<<<dim3(DMOD / 256, 32), blk, 0, stream>>>(t1, psum, psq);
  bn_finalize<<<DMOD / 256, blk, 0, stream>>>(psum, psq, meanv, rstdv);
  bn_apply_lsq<float><<<ROWS * DMOD / 256, blk, 0, stream>>>(
      t1, meanv, rstdv, bn2_g, bn2_b, f3, y_out);
  // --- fa2 adapter chain on y (overwrites t1 scratch) ---
  gemm_q<float, float, float><<<grd(ROWS, 64), blk, 0, stream>>>(
      y_out, fa2_w1, nullptr, fa2_b1, nullptr, nulf, u1, ROWS, 64, DMOD);
  gemm_q<float, float, float><<<grd(ROWS, 64), blk, 0, stream>>>(
      u1, fa2_w2, nullptr, fa2_b2, nullptr, nulf, u2, ROWS, 64, 64);
  gemm_q<float, float, float><<<grd(ROWS, DMOD), blk, 0, stream>>>(
      u2, fa2_w3, nullptr, fa2_b3, nullptr, y_out, fa2_out, ROWS, DMOD, 64);
}